// Round 3
// baseline (436.013 us; speedup 1.0000x reference)
//
#include <hip/hip_runtime.h>
#include <stdint.h>
#include <math.h>

typedef _Float16 f16;
typedef _Float16 f16x8 __attribute__((ext_vector_type(8)));
typedef float f32x4 __attribute__((ext_vector_type(4)));

#define KD 704
#define NPTS 8192

typedef const unsigned __attribute__((address_space(1)))* gas_ptr;
typedef unsigned __attribute__((address_space(3)))* las_ptr;

__device__ inline void gld16(const void* g, void* l) {
  __builtin_amdgcn_global_load_lds((gas_ptr)g, (las_ptr)l, 16, 0, 0);
}

__device__ inline unsigned long long packkey(float v, int idx) {
  unsigned b = __float_as_uint(v);
  b ^= ((unsigned)((int)b >> 31)) | 0x80000000u;  // monotone float->uint
  return ((unsigned long long)b << 32) | (unsigned)(~idx);  // ~idx: ties -> smaller idx wins
}

// ---- kernel 1: column norms (scaled by 256) + zero the atomic top-1 slots ----
__global__ void k_norm_init(const float* __restrict__ A, const float* __restrict__ B,
                            float* __restrict__ invA, float* __restrict__ invB,
                            unsigned long long* rowbest, unsigned long long* colbest) {
  int g = blockIdx.x * 256 + threadIdx.x;  // 0..16383
  const float* M = (g < NPTS) ? A : B;
  int c = g & (NPTS - 1);
  float ss = 0.f;
  for (int d = 0; d < KD; ++d) {
    float x = M[(size_t)d * NPTS + c];
    ss = fmaf(x, x, ss);
  }
  float inv = 256.0f / sqrtf(ss);  // fold split-scale S=256 into the normalization
  if (g < NPTS) { invA[c] = inv; rowbest[c] = 0ull; }
  else          { invB[c] = inv; colbest[c] = 0ull; }
}

// ---- kernel 2: transpose (D,N)->(N,D), normalize, fp16 hi/lo split ----
__global__ void k_split(const float* __restrict__ A, const float* __restrict__ B,
                        const float* __restrict__ invA, const float* __restrict__ invB,
                        f16* __restrict__ Ahi, f16* __restrict__ Alo,
                        f16* __restrict__ Bhi, f16* __restrict__ Blo) {
  __shared__ float t[32][33];
  int z = blockIdx.z;
  const float* M   = z ? B    : A;
  const float* inv = z ? invB : invA;
  f16* Hi = z ? Bhi : Ahi;
  f16* Lo = z ? Blo : Alo;
  int c0 = blockIdx.x * 32, d0 = blockIdx.y * 32;
  int tx = threadIdx.x & 31, ty = threadIdx.x >> 5;
  #pragma unroll
  for (int s = 0; s < 4; ++s)
    t[ty + s * 8][tx] = M[(size_t)(d0 + ty + s * 8) * NPTS + (c0 + tx)];
  __syncthreads();
  #pragma unroll
  for (int s = 0; s < 4; ++s) {
    int i = c0 + ty + s * 8;
    float v = t[tx][ty + s * 8] * inv[i];
    f16 hi = (f16)v;
    f16 lo = (f16)(v - (float)hi);
    size_t o = (size_t)i * KD + (d0 + tx);
    Hi[o] = hi;
    Lo[o] = lo;
  }
}

// ---- kernel 3: 128x128-tile GEMM (f16 hi/lo, 3 products) + fused top-1 atomics ----
__global__ __launch_bounds__(256, 2)
void k_gemm_top1(const f16* __restrict__ Ahi, const f16* __restrict__ Alo,
                 const f16* __restrict__ Bhi, const f16* __restrict__ Blo,
                 unsigned long long* rowbest, unsigned long long* colbest) {
  // LDS tiles: [128 rows][64 k] f16 = 128B rows; XOR-8 swizzle on 16B slots.
  __shared__ f16 sAh[128 * 64];
  __shared__ f16 sAl[128 * 64];
  __shared__ f16 sBh[128 * 64];
  __shared__ f16 sBl[128 * 64];

  const int tid = threadIdx.x, lane = tid & 63, wave = tid >> 6;
  const int bj = blockIdx.x & 63, bi = blockIdx.x >> 6;
  const int wr = wave >> 1, wc = wave & 1;

  f32x4 acc[4][4] = {};

  // staging: wave w stages rows [w*32, w*32+32) of each tile; 4 instrs/tile.
  // LDS dest is linear (base + lane*16); global source is pre-swizzled:
  // data for (row, col-slot c) lands at LDS slot c ^ (row&7).
  const int srow = wave * 32 + (lane >> 3);        // q adds 8 -> (srow+q*8)&7 == srow&7
  const int cs   = ((lane & 7) ^ (srow & 7)) * 16; // swizzled source slot, bytes
  const size_t rowbytes = (size_t)KD * 2;          // 1408
  const char* pAh = (const char*)Ahi + (size_t)(bi * 128 + srow) * rowbytes + cs;
  const char* pAl = (const char*)Alo + (size_t)(bi * 128 + srow) * rowbytes + cs;
  const char* pBh = (const char*)Bhi + (size_t)(bj * 128 + srow) * rowbytes + cs;
  const char* pBl = (const char*)Blo + (size_t)(bj * 128 + srow) * rowbytes + cs;
  const unsigned lbase = wave * 4096;  // bytes; + q*1024; HW adds lane*16

  for (int ks = 0; ks < 11; ++ks) {
    const size_t kb = (size_t)ks * 128;  // k0 * 2 bytes
    #pragma unroll
    for (int q = 0; q < 4; ++q) {
      size_t go = kb + (size_t)q * 8 * rowbytes;
      unsigned lo_ = lbase + q * 1024;
      gld16(pAh + go, (char*)sAh + lo_);
      gld16(pAl + go, (char*)sAl + lo_);
      gld16(pBh + go, (char*)sBh + lo_);
      gld16(pBl + go, (char*)sBl + lo_);
    }
    __syncthreads();  // drains vmcnt before barrier (compiler-inserted)

    #pragma unroll
    for (int kk = 0; kk < 2; ++kk) {
      f16x8 ah[4], al[4], bh[4], bl[4];
      const int sa = ((kk * 4 + (lane >> 4)) ^ (lane & 7)) * 16;  // swizzled read slot
      #pragma unroll
      for (int a = 0; a < 4; ++a) {
        int row = wr * 64 + a * 16 + (lane & 15);
        ah[a] = *(const f16x8*)((const char*)sAh + row * 128 + sa);
        al[a] = *(const f16x8*)((const char*)sAl + row * 128 + sa);
      }
      #pragma unroll
      for (int b = 0; b < 4; ++b) {
        int row = wc * 64 + b * 16 + (lane & 15);
        bh[b] = *(const f16x8*)((const char*)sBh + row * 128 + sa);
        bl[b] = *(const f16x8*)((const char*)sBl + row * 128 + sa);
      }
      #pragma unroll
      for (int a = 0; a < 4; ++a)
        #pragma unroll
        for (int b = 0; b < 4; ++b) {
          acc[a][b] = __builtin_amdgcn_mfma_f32_16x16x32_f16(ah[a], bh[b], acc[a][b], 0, 0, 0);
          acc[a][b] = __builtin_amdgcn_mfma_f32_16x16x32_f16(ah[a], bl[b], acc[a][b], 0, 0, 0);
          acc[a][b] = __builtin_amdgcn_mfma_f32_16x16x32_f16(al[a], bh[b], acc[a][b], 0, 0, 0);
        }
    }
    __syncthreads();
  }

  // ---- fused top-1 reduction. C/D layout: col = lane&15, row = (lane>>4)*4 + reg ----
  const float scale = 1.0f / 65536.0f;  // undo S^2
  const int R0 = bi * 128 + wr * 64;
  const int C0 = bj * 128 + wc * 64;

  // rows: each 16-lane group (lane>>4) holds 4 rows (reg) x 4 (a); cols across lane&15 and b
  #pragma unroll
  for (int a = 0; a < 4; ++a) {
    #pragma unroll
    for (int r = 0; r < 4; ++r) {
      float bv = acc[a][0][r];
      int bjx = C0 + (lane & 15);
      #pragma unroll
      for (int b = 1; b < 4; ++b) {
        float v = acc[a][b][r];
        if (v > bv) { bv = v; bjx = C0 + b * 16 + (lane & 15); }
      }
      unsigned long long key = packkey(bv * scale, bjx);
      #pragma unroll
      for (int off = 1; off < 16; off <<= 1) {
        unsigned long long o = __shfl_xor(key, off);
        if (o > key) key = o;
      }
      if ((lane & 15) == 0) {
        int row = R0 + a * 16 + (lane >> 4) * 4 + r;
        atomicMax(&rowbest[row], key);
      }
    }
  }
  // cols: col = C0 + b*16 + (lane&15); rows spread over (lane>>4) groups and regs
  #pragma unroll
  for (int b = 0; b < 4; ++b) {
    unsigned long long key = 0ull;
    #pragma unroll
    for (int a = 0; a < 4; ++a)
      #pragma unroll
      for (int r = 0; r < 4; ++r) {
        int i = R0 + a * 16 + (lane >> 4) * 4 + r;
        unsigned long long k2 = packkey(acc[a][b][r] * scale, i);
        if (k2 > key) key = k2;
      }
    unsigned long long o = __shfl_xor(key, 16); if (o > key) key = o;
    o = __shfl_xor(key, 32); if (o > key) key = o;
    if (lane < 16) atomicMax(&colbest[C0 + b * 16 + lane], key);
  }
}

// ---- kernel 4: mutual-NN mask + output assembly (all f32) ----
__global__ void k_epilogue(const unsigned long long* __restrict__ rowbest,
                           const unsigned long long* __restrict__ colbest,
                           float* __restrict__ out) {
  int i = blockIdx.x * 256 + threadIdx.x;  // 0..8191
  unsigned long long rk = rowbest[i];
  int j = (int)(~(unsigned)rk);
  unsigned hb = (unsigned)(rk >> 32);
  hb ^= (hb >> 31) ? 0x80000000u : 0xFFFFFFFFu;
  float sim = __uint_as_float(hb);
  unsigned long long ck = colbest[j];
  int nn21 = (int)(~(unsigned)ck);
  bool m = (nn21 == i);
  out[2 * i]     = m ? (float)i : -1.0f;
  out[2 * i + 1] = m ? (float)j : -1.0f;
  out[2 * NPTS + i] = m ? sim : 0.0f;
  out[3 * NPTS + i] = m ? 1.0f : 0.0f;
}

extern "C" void kernel_launch(void* const* d_in, const int* in_sizes, int n_in,
                              void* d_out, int out_size, void* d_ws, size_t ws_size,
                              hipStream_t stream) {
  const float* A = (const float*)d_in[0];
  const float* B = (const float*)d_in[1];
  char* ws = (char*)d_ws;

  const size_t SPLIT = (size_t)NPTS * KD * 2;  // 11,534,336 B per array
  unsigned long long* rowbest = (unsigned long long*)(ws);
  unsigned long long* colbest = (unsigned long long*)(ws + 65536);
  float* invA = (float*)(ws + 131072);
  float* invB = (float*)(ws + 163840);
  f16* Ahi = (f16*)(ws + 196608);
  f16* Alo = (f16*)(ws + 196608 + SPLIT);
  f16* Bhi = (f16*)(ws + 196608 + 2 * SPLIT);
  f16* Blo = (f16*)(ws + 196608 + 3 * SPLIT);

  k_norm_init<<<64, 256, 0, stream>>>(A, B, invA, invB, rowbest, colbest);
  dim3 g2(NPTS / 32, KD / 32, 2);
  k_split<<<g2, 256, 0, stream>>>(A, B, invA, invB, Ahi, Alo, Bhi, Blo);
  k_gemm_top1<<<4096, 256, 0, stream>>>(Ahi, Alo, Bhi, Blo, rowbest, colbest);
  k_epilogue<<<NPTS / 256, 256, 0, stream>>>(rowbest, colbest, (float*)d_out);
}